// Round 9
// baseline (249.491 us; speedup 1.0000x reference)
//
#include <hip/hip_runtime.h>
#include <stdint.h>

// ksparse: per row of 4096x8192 f32, threshold = 513th largest (k=512),
// out = x * (x > thresh). Two-kernel split to kill the load/select/write
// phase convoy of the monolithic version:
//   K1: per-row exact radix select (11-bit main pass + compaction + 3x7-bit
//       tails) -> one float threshold per row into d_ws. Nearly pure read
//       stream + short LDS tail.
//   K2: pure streaming mask apply, out = in > thr[row] ? in : 0.

constexpr int COLS  = 8192;
constexpr int TPB   = 256;
constexpr int EPT   = COLS / TPB;  // 32 elements per thread
constexpr int VPT   = EPT / 4;     // 8 float4 per thread
constexpr int NBIN0 = 2048;        // main-pass bins (11 bits)
constexpr int CAP   = 2048;        // candidate buffer capacity (reuses replica 1)

__device__ __forceinline__ uint32_t map_f32(uint32_t u) {
  return (u & 0x80000000u) ? ~u : (u | 0x80000000u);
}
__device__ __forceinline__ float unmap_f32(uint32_t m) {
  return __uint_as_float((m & 0x80000000u) ? (m ^ 0x80000000u) : ~m);
}

__global__ __launch_bounds__(TPB)
void thresh_kernel(const float* __restrict__ in, const int* __restrict__ kptr,
                   float* __restrict__ thr) {
  __shared__ __align__(16) uint32_t hist[2 * NBIN0]; // replica0 | replica1(->cand)
  __shared__ uint32_t th[3 * 128];
  __shared__ uint32_t wtot[4];
  __shared__ uint32_t s_packed;
  __shared__ uint32_t s_cnt;
  __shared__ uint32_t s_sel[3];

  const int t    = threadIdx.x;
  const int wave = t >> 6;
  const int lane = t & 63;
  const size_t rowbase = (size_t)blockIdx.x * COLS;

  // issue all global loads first; LDS zeroing overlaps their latency
  const float4* inp = (const float4*)(in + rowbase);
  float4 v[VPT];
#pragma unroll
  for (int i = 0; i < VPT; ++i) v[i] = inp[t + i * TPB];

  uint4* h4 = (uint4*)hist;
#pragma unroll
  for (int i = 0; i < 4; ++i) h4[t + i * TPB] = make_uint4(0u, 0u, 0u, 0u);
  th[t] = 0u;
  if (t < 128) th[256 + t] = 0u;
  if (t == 0) { s_packed = 0u; s_cnt = 0u; }
  uint32_t kk = (uint32_t)(*kptr) + 1u;
  __syncthreads();

  // main pass: map + 2048-bin histogram (2 replicas, one per wave-pair)
  uint32_t m[EPT];
  uint32_t* h = &hist[(wave >> 1) * NBIN0];
#pragma unroll
  for (int i = 0; i < VPT; ++i) {
    m[4 * i + 0] = map_f32(__float_as_uint(v[i].x));
    m[4 * i + 1] = map_f32(__float_as_uint(v[i].y));
    m[4 * i + 2] = map_f32(__float_as_uint(v[i].z));
    m[4 * i + 3] = map_f32(__float_as_uint(v[i].w));
    atomicAdd(&h[m[4 * i + 0] >> 21], 1u);
    atomicAdd(&h[m[4 * i + 1] >> 21], 1u);
    atomicAdd(&h[m[4 * i + 2] >> 21], 1u);
    atomicAdd(&h[m[4 * i + 3] >> 21], 1u);
  }
  __syncthreads();

  // scan: 8 bins/thread, wave suffix, packed argmax
  {
    const uint4* hv = (const uint4*)hist;
    uint4 a0 = hv[2 * t], a1 = hv[2 * t + 1];
    uint4 b0 = hv[512 + 2 * t], b1 = hv[512 + 2 * t + 1];
    uint32_t c0 = a0.x + b0.x, c1 = a0.y + b0.y, c2 = a0.z + b0.z, c3 = a0.w + b0.w;
    uint32_t c4 = a1.x + b1.x, c5 = a1.y + b1.y, c6 = a1.z + b1.z, c7 = a1.w + b1.w;
    uint32_t sl[8];
    sl[7] = c7;         sl[6] = sl[7] + c6; sl[5] = sl[6] + c5; sl[4] = sl[5] + c4;
    sl[3] = sl[4] + c3; sl[2] = sl[3] + c2; sl[1] = sl[2] + c1; sl[0] = sl[1] + c0;
    const uint32_t total = sl[0];

    uint32_t s = total;
#pragma unroll
    for (int off = 1; off < 64; off <<= 1) {
      uint32_t tmp = __shfl_down(s, off, 64);
      s += (lane + off < 64) ? tmp : 0u;
    }
    if (lane == 0) wtot[wave] = s;
    __syncthreads();

    uint32_t hi = 0;
#pragma unroll
    for (int w = 1; w < 4; ++w)
      if (w > wave) hi += wtot[w];
    const uint32_t excl = hi + (s - total);

    int best = -1;
#pragma unroll
    for (int j = 7; j >= 0; --j)
      if (best < 0 && excl + sl[j] >= kk) best = j;
    if (best >= 0) {
      const uint32_t above = excl + ((best < 7) ? sl[best + 1] : 0u);
      atomicMax(&s_packed, ((uint32_t)(t * 8 + best) << 14) | above);
    }
  }
  __syncthreads();

  const uint32_t pk = s_packed;
  const uint32_t d0 = pk >> 14;
  kk -= (pk & 0x3FFFu);

  // compact candidates (top-11 bits == d0) into dead replica-1 LDS
  uint32_t* cand = &hist[NBIN0];
#pragma unroll
  for (int i = 0; i < EPT; ++i) {
    if ((m[i] >> 21) == d0) {
      uint32_t idx = atomicAdd(&s_cnt, 1u);
      if (idx < CAP) cand[idx] = m[i] & 0x1FFFFFu;
    }
  }
  __syncthreads();
  const uint32_t Cc = (s_cnt < (uint32_t)CAP) ? s_cnt : (uint32_t)CAP;

  // three 7-bit tail passes over the candidates
  uint32_t tpref = 0;
#pragma unroll 1
  for (int j = 0; j < 3; ++j) {
    const int dsh = 14 - 7 * j;
    uint32_t* thj = &th[j * 128];
    for (uint32_t idx = t; idx < Cc; idx += TPB) {
      const uint32_t c = cand[idx];
      const bool ok = (j == 0) || ((c >> (dsh + 7)) == tpref);
      if (ok) atomicAdd(&thj[(c >> dsh) & 127u], 1u);
    }
    __syncthreads();

    if (wave == 0) {
      uint32_t a = thj[lane], b = thj[64 + lane];
      uint32_t sb = b, sa = a;
#pragma unroll
      for (int off = 1; off < 64; off <<= 1) {
        uint32_t t1 = __shfl_down(sb, off, 64);
        uint32_t t2 = __shfl_down(sa, off, 64);
        const bool inr = (lane + off < 64);
        sb += inr ? t1 : 0u;
        sa += inr ? t2 : 0u;
      }
      const uint32_t tb = __shfl(sb, 0, 64);
      sa += tb;
      const unsigned long long mb = __ballot(sb >= kk);
      uint32_t d, ab;
      if (mb) {
        const int hb = 63 - __builtin_clzll(mb);
        const uint32_t nx = __shfl(sb, (hb + 1) & 63, 64);
        d = 64 + hb;
        ab = (hb == 63) ? 0u : nx;
      } else {
        const unsigned long long ma = __ballot(sa >= kk);
        const int ha = 63 - __builtin_clzll(ma);
        const uint32_t nx = __shfl(sa, (ha + 1) & 63, 64);
        d = (uint32_t)ha;
        ab = (ha == 63) ? tb : nx;
      }
      if (lane == 0) s_sel[j] = (d << 16) | ab;
    }
    __syncthreads();

    const uint32_t sel = s_sel[j];
    tpref = (tpref << 7) | (sel >> 16);
    kk -= (sel & 0xFFFFu);
  }

  if (t == 0) {
    const uint32_t T = (d0 << 21) | tpref; // mapped bits of rank-(k+1) element
    thr[blockIdx.x] = unmap_f32(T);
  }
}

__global__ __launch_bounds__(TPB)
void apply_kernel(const float* __restrict__ in, const float* __restrict__ thr,
                  float* __restrict__ out) {
  const int t = threadIdx.x;
  const size_t rowbase = (size_t)blockIdx.x * COLS;
  const float tv = thr[blockIdx.x]; // wave-uniform scalar load
  const float4* ip = (const float4*)(in + rowbase);
  float4* op = (float4*)(out + rowbase);
#pragma unroll
  for (int i = 0; i < VPT; ++i) {
    float4 v = ip[t + i * TPB];
    v.x = (v.x > tv) ? v.x : 0.0f;
    v.y = (v.y > tv) ? v.y : 0.0f;
    v.z = (v.z > tv) ? v.z : 0.0f;
    v.w = (v.w > tv) ? v.w : 0.0f;
    op[t + i * TPB] = v;
  }
}

extern "C" void kernel_launch(void* const* d_in, const int* in_sizes, int n_in,
                              void* d_out, int out_size, void* d_ws, size_t ws_size,
                              hipStream_t stream) {
  const float* in  = (const float*)d_in[0];
  const int*   k   = (const int*)d_in[1];
  float*       out = (float*)d_out;
  float*       thr = (float*)d_ws; // 4096 floats = 16 KB scratch
  int rows = in_sizes[0] / COLS;
  if (rows < 1) rows = 1;
  thresh_kernel<<<rows, TPB, 0, stream>>>(in, k, thr);
  apply_kernel<<<rows, TPB, 0, stream>>>(in, thr, out);
}